// Round 11
// baseline (181.474 us; speedup 1.0000x reference)
//
#include <hip/hip_runtime.h>
#include <cstdint>
#include <cstddef>

// ---------------------------------------------------------------------------
// NeighborTransferModel fused pipeline for MI355X (gfx950) — round 11
//
// = round 10 with gemm1 re-dimensioned to 1024 threads / 16 waves
//   (4 waves/SIMD, wave tile 64x64) — same BM=128 x BN=512 x BK=64 tile,
//   same 160KB dbuf LDS, same traffic; the extra waves/SIMD provide the
//   latency hiding (m114 mechanism) that 8 waves (2/SIMD) could not.
//   Simple 2-barrier loop (r2 structure).  Fused cosine-sim + layer-2/3
//   tail kept (re-tiled for 16 waves).
// ---------------------------------------------------------------------------

typedef __attribute__((ext_vector_type(8))) short s16x8;
typedef __attribute__((ext_vector_type(4))) float f32x4;

static __device__ __forceinline__ unsigned short f2bf(float f) {
  unsigned u = __float_as_uint(f);
  u += 0x7fffu + ((u >> 16) & 1u);   // round-to-nearest-even
  return (unsigned short)(u >> 16);
}

static __device__ __forceinline__ void glds16(const void* g, void* l) {
  __builtin_amdgcn_global_load_lds(
      (const __attribute__((address_space(1))) void*)g,
      (__attribute__((address_space(3))) void*)l, 16, 0, 0);
}

// ---------------------------------------------------------------------------
// Merged prep kernel (unchanged from r10).
// ---------------------------------------------------------------------------
__global__ void prep_k(const float* __restrict__ qp, const float* __restrict__ qd,
                       unsigned short* __restrict__ Aq, float* __restrict__ qn,
                       const float* __restrict__ w1, const float* __restrict__ d1,
                       const float* __restrict__ be1, const float* __restrict__ w2,
                       const float* __restrict__ d2,
                       unsigned short* __restrict__ Bt1,
                       unsigned short* __restrict__ Btq,
                       unsigned short* __restrict__ Bt2c) {
  const int t = threadIdx.x;
  if (blockIdx.x < 1024) {
    const int n = blockIdx.x;
    const float4* qp4 = (const float4*)(qp + (size_t)n * 1024);
    float4 v = qp4[t];
    ushort4 o4;
    o4.x = f2bf(v.x); o4.y = f2bf(v.y); o4.z = f2bf(v.z); o4.w = f2bf(v.w);
    *(ushort4*)(Aq + (size_t)n * 1536 + t * 4) = o4;
    const float2* qd2 = (const float2*)(qd + (size_t)n * 512);
    float2 w = qd2[t];
    ushort2 o2; o2.x = f2bf(w.x); o2.y = f2bf(w.y);
    *(ushort2*)(Aq + (size_t)n * 1536 + 1024 + t * 2) = o2;
    float ss = w.x * w.x + w.y * w.y;
    #pragma unroll
    for (int m = 32; m >= 1; m >>= 1) ss += __shfl_xor(ss, m);
    __shared__ float sr[4];
    if ((t & 63) == 0) sr[t >> 6] = ss;
    __syncthreads();
    if (t == 0) qn[n] = sqrtf(sr[0] + sr[1] + sr[2] + sr[3]);
    return;
  }
  const int NB1 = 512 * 1536, NBQ = 768 * 1536, NB2 = 256 * 256;
  const int nb = gridDim.x - 1024;
  for (int idx = (blockIdx.x - 1024) * 256 + t; idx < NB1 + NBQ + NB2;
       idx += nb * 256) {
    if (idx < NB1) {
      int c = idx / 1536, j = idx - c * 1536;
      const float* W = (c < 256) ? w1 : d1;
      int cc = c & 255;
      float v;
      if (j < 1024) v = W[(1024 + j) * 256 + cc] - W[(2048 + j) * 256 + cc];
      else { int jd = j - 1024; v = W[(3584 + jd) * 256 + cc] - W[(4096 + jd) * 256 + cc]; }
      Bt1[idx] = f2bf(v);
    } else if (idx < NB1 + NBQ) {
      int i2 = idx - NB1;
      int c = i2 / 1536, j = i2 - c * 1536;
      float v;
      if (c < 512) {
        const float* W = (c < 256) ? w1 : d1;
        int cc = c & 255;
        if (j < 1024) v = W[j * 256 + cc] + W[(2048 + j) * 256 + cc];
        else { int jd = j - 1024; v = W[(3072 + jd) * 256 + cc] + W[(4096 + jd) * 256 + cc]; }
      } else {
        v = be1[j * 256 + (c - 512)];
      }
      Btq[i2] = f2bf(v);
    } else {
      int i2 = idx - NB1 - NBQ;
      int o = i2 >> 8, j = i2 & 255;
      float v = (o < 128) ? w2[j * 128 + o] : d2[j * 128 + (o - 128)];
      Bt2c[i2] = f2bf(v);
    }
  }
}

// ---------------------------------------------------------------------------
// GEMM-0: query GEMM (unchanged). M=1024, Kd=1536, NC=768.
// ---------------------------------------------------------------------------
__global__ __launch_bounds__(256) void gemm0_k(
    const unsigned short* __restrict__ abf, const unsigned short* __restrict__ Bt,
    const float* __restrict__ wb1, const float* __restrict__ db1,
    const float* __restrict__ beb1, float* __restrict__ uq_out) {
  __shared__ short As[128 * 64];
  __shared__ short Bs[128 * 64];
  const int tid = threadIdx.x;
  const int l = tid & 63, w = tid >> 6;
  const int wr = w >> 1, wc = w & 1;
  const int br = blockIdx.x, bc = blockIdx.y;
  const int c0 = bc * 128;
  f32x4 acc[4][4] = {};

  for (int kt = 0; kt < 24; ++kt) {
    const int k0 = kt * 64;
    __syncthreads();
    #pragma unroll
    for (int rep = 0; rep < 4; ++rep) {
      int q = rep * 256 + tid;
      int row = q >> 3, slot = q & 7;
      int kc = slot ^ (row & 7);
      int gk = k0 + kc * 8;
      long grow = (long)br * 128 + row;
      s16x8 pk = *(const s16x8*)(abf + grow * 1536 + gk);
      *(s16x8*)(&As[q * 8]) = pk;
      s16x8 pb = *(const s16x8*)(Bt + (long)(c0 + row) * 1536 + gk);
      *(s16x8*)(&Bs[q * 8]) = pb;
    }
    __syncthreads();
    #pragma unroll
    for (int kh = 0; kh < 2; ++kh) {
      s16x8 af[4], bfr[4];
      #pragma unroll
      for (int mi = 0; mi < 4; ++mi) {
        int ra = wr * 64 + mi * 16 + (l & 15);
        int sidx = (kh * 4 + (l >> 4)) ^ (ra & 7);
        af[mi] = *(const s16x8*)(&As[ra * 64 + sidx * 8]);
      }
      #pragma unroll
      for (int ni = 0; ni < 4; ++ni) {
        int rb = wc * 64 + ni * 16 + (l & 15);
        int sidx = (kh * 4 + (l >> 4)) ^ (rb & 7);
        bfr[ni] = *(const s16x8*)(&Bs[rb * 64 + sidx * 8]);
      }
      #pragma unroll
      for (int mi = 0; mi < 4; ++mi)
        #pragma unroll
        for (int ni = 0; ni < 4; ++ni)
          acc[mi][ni] = __builtin_amdgcn_mfma_f32_16x16x32_bf16(
              af[mi], bfr[ni], acc[mi][ni], 0, 0, 0);
    }
  }
  #pragma unroll
  for (int mi = 0; mi < 4; ++mi)
    #pragma unroll
    for (int ni = 0; ni < 4; ++ni)
      #pragma unroll
      for (int r = 0; r < 4; ++r) {
        int rowl = wr * 64 + mi * 16 + (l >> 4) * 4 + r;
        int coll = wc * 64 + ni * 16 + (l & 15);
        long grow = (long)br * 128 + rowl;
        int gcol = c0 + coll;
        float b = (gcol < 256) ? wb1[gcol]
                 : (gcol < 512) ? db1[gcol - 256] : beb1[gcol - 512];
        uq_out[grow * 768 + gcol] = acc[mi][ni][r] + b;
      }
}

// ---------------------------------------------------------------------------
// GEMM-1 (fused): neighbor GEMM + layer-2 + layer-3.
// 1024 thr / 16 waves (4/SIMD).  BM=128 x BN=512 x BK=64, 160KB dbuf.
// Wave (wr=w>>3, wc=w&7) owns 64x64.  Simple 2-barrier loop.
// ---------------------------------------------------------------------------
__global__ __launch_bounds__(1024, 4) void gemm1_k(
    const float* __restrict__ Anp, const float* __restrict__ And,
    const unsigned short* __restrict__ Bt,
    const float* __restrict__ uq, const float* __restrict__ aff,
    const float* __restrict__ ppr, const float* __restrict__ trs,
    const float* __restrict__ qd, const float* __restrict__ qn,
    const float* __restrict__ w1, const float* __restrict__ d1,
    const unsigned short* __restrict__ Bt2c,
    const float* __restrict__ wb2, const float* __restrict__ db2,
    const float* __restrict__ w3, const float* __restrict__ wb3,
    const float* __restrict__ d3, const float* __restrict__ db3,
    float* __restrict__ ld) {
  __shared__ short As[2][128 * 64];   // 16 KB x2
  __shared__ short Bs[2][512 * 64];   // 64 KB x2  -> exactly 160 KiB
  const int tid = threadIdx.x;
  const int l = tid & 63, w = tid >> 6;
  const int wr = w >> 3, wc = w & 7;           // wave tile: rows wr*64, cols wc*64
  const long br = blockIdx.x;
  const int arow = tid >> 3, aseg = tid & 7;   // A staging: 128 rows x 8 segs
  const long agrow = br * 128 + arow;
  const long an = agrow >> 5;
  const int lc = l & 15, lk = l >> 4;

  f32x4 acc[4][4] = {};
  float areg[8], qreg[8];
  float dotp = 0.f, nsp = 0.f;

  auto stageB = [&](int buf, int kt) {
    const int k0 = kt * 64;
    #pragma unroll
    for (int i = 0; i < 4; ++i) {
      int q = i * 1024 + tid;                  // [0,4096) 16B chunks
      int row = q >> 3, slot = q & 7;
      const unsigned short* src =
          Bt + (size_t)row * 1536 + k0 + ((slot ^ (row & 7)) * 8);
      glds16(src, &Bs[buf][q * 8]);
    }
  };
  auto loadA = [&](int kt) {
    const int k0 = kt * 64 + aseg * 8;
    const float* src = (k0 < 1024) ? (Anp + agrow * 1024 + k0)
                                   : (And + agrow * 512 + (k0 - 1024));
    float4 v0 = ((const float4*)src)[0];
    float4 v1 = ((const float4*)src)[1];
    areg[0] = v0.x; areg[1] = v0.y; areg[2] = v0.z; areg[3] = v0.w;
    areg[4] = v1.x; areg[5] = v1.y; areg[6] = v1.z; areg[7] = v1.w;
    if (kt >= 16) {                      // nd region: qd for fused cosine-sim
      const float* qs = qd + an * 512 + (k0 - 1024);
      float4 u0 = ((const float4*)qs)[0];
      float4 u1 = ((const float4*)qs)[1];
      qreg[0] = u0.x; qreg[1] = u0.y; qreg[2] = u0.z; qreg[3] = u0.w;
      qreg[4] = u1.x; qreg[5] = u1.y; qreg[6] = u1.z; qreg[7] = u1.w;
    }
  };
  auto writeA = [&](int buf, int kt) {
    if (kt >= 16) {
      #pragma unroll
      for (int j = 0; j < 8; ++j) {
        dotp += areg[j] * qreg[j];
        nsp  += areg[j] * areg[j];
      }
    }
    int slot = aseg ^ (arow & 7);
    s16x8 pk;
    #pragma unroll
    for (int e = 0; e < 8; ++e) pk[e] = (short)f2bf(areg[e]);
    *(s16x8*)(&As[buf][arow * 64 + slot * 8]) = pk;
  };

  // ---- prologue: stage buffer 0, full drain ----
  stageB(0, 0); loadA(0); writeA(0, 0);
  __syncthreads();

  for (int kt = 0; kt < 24; ++kt) {
    const int cur = kt & 1, nxt = cur ^ 1;
    if (kt < 23) { stageB(nxt, kt + 1); loadA(kt + 1); }
    #pragma unroll
    for (int kh = 0; kh < 2; ++kh) {
      s16x8 af[4], bfr[4];
      #pragma unroll
      for (int mi = 0; mi < 4; ++mi) {
        int ra = wr * 64 + mi * 16 + lc;
        int sl = (kh * 4 + lk) ^ (ra & 7);
        af[mi] = *(const s16x8*)(&As[cur][ra * 64 + sl * 8]);
      }
      #pragma unroll
      for (int ni = 0; ni < 4; ++ni) {
        int rb = wc * 64 + ni * 16 + lc;
        int sl = (kh * 4 + lk) ^ (rb & 7);
        bfr[ni] = *(const s16x8*)(&Bs[cur][rb * 64 + sl * 8]);
      }
      __builtin_amdgcn_s_setprio(1);
      #pragma unroll
      for (int mi = 0; mi < 4; ++mi)
        #pragma unroll
        for (int ni = 0; ni < 4; ++ni)
          acc[mi][ni] = __builtin_amdgcn_mfma_f32_16x16x32_bf16(
              af[mi], bfr[ni], acc[mi][ni], 0, 0, 0);
      __builtin_amdgcn_s_setprio(0);
    }
    if (kt < 23) writeA(nxt, kt + 1);
    __syncthreads();
  }

  // ---- cosine-sim reduce (8 segs: xor 1,2,4); simLds aliases As[0] ----
  float* simLds = (float*)&As[0][0];
  float dv = dotp, nv = nsp;
  dv += __shfl_xor(dv, 1); dv += __shfl_xor(dv, 2); dv += __shfl_xor(dv, 4);
  nv += __shfl_xor(nv, 1); nv += __shfl_xor(nv, 2); nv += __shfl_xor(nv, 4);
  if (aseg == 0) {
    float qv = qn[an];
    simLds[arow] = dv / (fmaxf(qv, 1e-8f) * fmaxf(sqrtf(nv), 1e-8f));
  }
  __syncthreads();

  // ---- step 1: h1 tile -> LDS (Bs region), low-3-bit chunk-XOR swizzle ----
  short* h1l = &Bs[0][0];
  #pragma unroll
  for (int mi = 0; mi < 4; ++mi) {
    #pragma unroll
    for (int r = 0; r < 4; ++r) {
      int rowl = wr * 64 + mi * 16 + lk * 4 + r;
      long grow = br * 128 + rowl;
      float sa = aff[grow], sp = ppr[grow], st = trs[grow];
      float ss = simLds[rowl];
      long n = grow >> 5;
      #pragma unroll
      for (int ni = 0; ni < 4; ++ni) {
        int gcol = wc * 64 + ni * 16 + lc;
        const float* W = (gcol < 256) ? w1 : d1;
        int cc2 = gcol & 255;
        float sv = sa * W[4608 * 256 + cc2] + sp * W[4609 * 256 + cc2]
                 + st * W[4610 * 256 + cc2] + ss * W[4611 * 256 + cc2];
        float x = acc[mi][ni][r] + uq[n * 768 + gcol] + sv;
        int chsw = (gcol >> 3) ^ (rowl & 7);
        h1l[rowl * 512 + chsw * 8 + (gcol & 7)] = (short)f2bf(fmaxf(x, 0.f));
      }
    }
  }
  __syncthreads();

  // ---- step 2: layer-2 GEMM from LDS.  16-wave re-tiling:
  //   rq = w>>2 (row quarter, 32 rows -> 2 m-tiles), oq = w&3 (64 outs).
  //   outs 0..127 (oq 0,1) = w-net (h1 cols 0..255);
  //   outs 128..255 (oq 2,3) = d-net (h1 cols 256..511). ----
  short* B2 = &As[0][0];                 // [256 out][64 kk] per chunk (32 KB)
  f32x4 acc2[2][4] = {};
  const int rq = w >> 2;
  const int oq = w & 3;
  const int ob = oq * 64;
  const int kbase = (oq < 2) ? 0 : 256;
  for (int cc = 0; cc < 4; ++cc) {
    #pragma unroll
    for (int i = 0; i < 2; ++i) {
      int q = i * 1024 + tid;            // [0,2048) 16B chunks
      int o = q >> 3, sl = q & 7;
      const unsigned short* src =
          Bt2c + (size_t)o * 256 + cc * 64 + ((sl ^ (o & 7)) * 8);
      glds16(src, &B2[q * 8]);
    }
    __syncthreads();                     // drain glds; B2 chunk ready
    #pragma unroll
    for (int kh = 0; kh < 2; ++kh) {
      s16x8 a2[2], b2f[4];
      #pragma unroll
      for (int mi = 0; mi < 2; ++mi) {
        int row = rq * 32 + mi * 16 + lc;
        int acol = kbase + cc * 64 + kh * 32 + lk * 8;
        int chsw = (acol >> 3) ^ (row & 7);
        a2[mi] = *(const s16x8*)(&h1l[row * 512 + chsw * 8]);
      }
      #pragma unroll
      for (int ni = 0; ni < 4; ++ni) {
        int o = ob + ni * 16 + lc;
        int sl = (kh * 4 + lk) ^ (o & 7);
        b2f[ni] = *(const s16x8*)(&B2[o * 64 + sl * 8]);
      }
      #pragma unroll
      for (int mi = 0; mi < 2; ++mi)
        #pragma unroll
        for (int ni = 0; ni < 4; ++ni)
          acc2[mi][ni] = __builtin_amdgcn_mfma_f32_16x16x32_bf16(
              a2[mi], b2f[ni], acc2[mi][ni], 0, 0, 0);
    }
    __syncthreads();                     // all reads of this chunk done
  }

  // ---- step 3: bias/relu + layer-3 dot; part aliases As (B2 dead) ----
  float coef[4], bb[4];
  #pragma unroll
  for (int ni = 0; ni < 4; ++ni) {
    int o = ob + ni * 16 + lc;
    coef[ni] = (o < 128) ? w3[o] : d3[o - 128];
    bb[ni]   = (o < 128) ? wb2[o] : db2[o - 128];
  }
  float* part = (float*)&As[0][0];       // [4 oq][128 rows]
  #pragma unroll
  for (int mi = 0; mi < 2; ++mi) {
    #pragma unroll
    for (int rr = 0; rr < 4; ++rr) {
      float p = 0.f;
      #pragma unroll
      for (int ni = 0; ni < 4; ++ni)
        p += fmaxf(acc2[mi][ni][rr] + bb[ni], 0.f) * coef[ni];
      p += __shfl_xor(p, 1); p += __shfl_xor(p, 2);
      p += __shfl_xor(p, 4); p += __shfl_xor(p, 8);
      if (lc == 0)
        part[oq * 128 + rq * 32 + mi * 16 + lk * 4 + rr] = p;
    }
  }
  __syncthreads();
  if (tid < 256) {
    int row = tid >> 1, hf = tid & 1;
    long grow = br * 128 + row;
    float v = hf ? (part[2 * 128 + row] + part[3 * 128 + row] + db3[0])
                 : (part[0 * 128 + row] + part[1 * 128 + row] + wb3[0]);
    ld[(size_t)hf * 32768 + grow] = v;
  }
}

// ---------------------------------------------------------------------------
// Finalize: masked softmax over K=32, prior, mu/sigma. (unchanged)
// ---------------------------------------------------------------------------
__global__ void finalize2_k(const float* __restrict__ uq, const float* __restrict__ ld,
                            const float* __restrict__ be2, const float* __restrict__ beb2,
                            const int* __restrict__ mask, const float* __restrict__ aff,
                            const float* __restrict__ lsg, float* __restrict__ out) {
  int n = blockIdx.x, t = threadIdx.x;
  __shared__ float s_red[4];
  float x = uq[(size_t)n * 768 + 512 + t];
  float pp = fmaxf(x, 0.f) * be2[t];
  #pragma unroll
  for (int m = 32; m >= 1; m >>= 1) pp += __shfl_xor(pp, m);
  if ((t & 63) == 0) s_red[t >> 6] = pp;
  __syncthreads();
  if (t < 64) {
    int kk = t & 31;
    int m = mask[n * 32 + kk];
    float lg = m ? ld[n * 32 + kk] : -1e9f;
    float dl = ld[32768 + n * 32 + kk];
    float mx = lg;
    #pragma unroll
    for (int mm = 16; mm >= 1; mm >>= 1) mx = fmaxf(mx, __shfl_xor(mx, mm));
    float e = expf(lg - mx);
    float s = e;
    #pragma unroll
    for (int mm = 16; mm >= 1; mm >>= 1) s += __shfl_xor(s, mm);
    float wgt = (e / s) * (m ? 1.f : 0.f);
    float nrm = wgt;
    #pragma unroll
    for (int mm = 16; mm >= 1; mm >>= 1) nrm += __shfl_xor(nrm, mm);
    wgt = (nrm > 0.f) ? wgt / fmaxf(nrm, 1e-8f) : 0.f;
    float tr = wgt * aff[n * 32 + kk];
    float co = wgt * dl;
    int am = m;
    #pragma unroll
    for (int mm = 16; mm >= 1; mm >>= 1) {
      tr += __shfl_xor(tr, mm);
      co += __shfl_xor(co, mm);
      am |= __shfl_xor(am, mm);
    }
    if (t == 0) {
      float prior = s_red[0] + s_red[1] + s_red[2] + s_red[3] + beb2[0] + 6.5f;
      float l0 = lsg[0];
      float sp = (l0 > 20.f) ? l0 : log1pf(expf(l0));
      float mu = am ? (tr + co) : prior;
      float sg = sp + (am ? 0.f : 0.15f) + 1e-4f;
      out[n] = mu;
      out[1024 + n] = sg;
    }
  }
}

// ---------------------------------------------------------------------------
extern "C" void kernel_launch(void* const* d_in, const int* in_sizes, int n_in,
                              void* d_out, int out_size, void* d_ws, size_t ws_size,
                              hipStream_t stream) {
  const float* np_ = (const float*)d_in[0];
  const float* nd_ = (const float*)d_in[1];
  const float* aff = (const float*)d_in[2];
  const float* ppr = (const float*)d_in[3];
  const float* trs = (const float*)d_in[4];
  const int*   msk = (const int*)d_in[5];
  const float* qp  = (const float*)d_in[6];
  const float* qd  = (const float*)d_in[7];
  const float* w1  = (const float*)d_in[8];
  const float* wb1 = (const float*)d_in[9];
  const float* w2  = (const float*)d_in[10];
  const float* wb2 = (const float*)d_in[11];
  const float* w3  = (const float*)d_in[12];
  const float* wb3 = (const float*)d_in[13];
  const float* d1  = (const float*)d_in[14];
  const float* db1 = (const float*)d_in[15];
  const float* d2  = (const float*)d_in[16];
  const float* db2 = (const float*)d_in[17];
  const float* d3  = (const float*)d_in[18];
  const float* db3 = (const float*)d_in[19];
  const float* be1 = (const float*)d_in[20];
  const float* beb1 = (const float*)d_in[21];
  const float* be2 = (const float*)d_in[22];
  const float* beb2 = (const float*)d_in[23];
  const float* lsg = (const float*)d_in[24];
  float* out = (float*)d_out;

  char* ws = (char*)d_ws;
  size_t off = 0;
  auto carve = [&](size_t bytes) -> void* {
    void* p = ws + off;
    off += (bytes + 511) & ~(size_t)511;
    return p;
  };
  float*          uq   = (float*)carve(1024ull * 768 * 4);
  float*          ld   = (float*)carve(2ull * 32768 * 4);
  unsigned short* Bt1  = (unsigned short*)carve(512ull * 1536 * 2);
  unsigned short* Btq  = (unsigned short*)carve(768ull * 1536 * 2);
  unsigned short* Bt2c = (unsigned short*)carve(256ull * 256 * 2);
  unsigned short* Aq   = (unsigned short*)carve(1024ull * 1536 * 2);
  float*          qn   = (float*)carve(1024ull * 4);
  (void)ws_size; (void)in_sizes; (void)n_in; (void)out_size;

  prep_k<<<3072, 256, 0, stream>>>(qp, qd, Aq, qn,
                                   w1, d1, be1, w2, d2, Bt1, Btq, Bt2c);

  gemm0_k<<<dim3(8, 6), 256, 0, stream>>>(Aq, Btq, wb1, db1, beb1, uq);

  gemm1_k<<<256, 1024, 0, stream>>>(np_, nd_, Bt1, uq, aff, ppr, trs,
                                    qd, qn, w1, d1,
                                    Bt2c, wb2, db2, w3, wb3, d3, db3, ld);

  finalize2_k<<<1024, 256, 0, stream>>>(uq, ld, be2, beb2, msk, aff, lsg, out);
}

// Round 12
// 123.954 us; speedup vs baseline: 1.4640x; 1.4640x over previous
//
#include <hip/hip_runtime.h>
#include <cstdint>
#include <cstddef>

// ---------------------------------------------------------------------------
// NeighborTransferModel fused pipeline for MI355X (gfx950) — round 12
//
// gemm1 K-loop: round-10 structure (family floor after 8 structural
// experiments; r11's 16-wave variant regressed 40% -> reverted).
// Round-12 changes:
//  (a) gemm0 re-tiled 64x64, grid 16x12 = 192 blocks (was 48) — 4x CU
//      coverage; both operands bf16 -> glds16 staging.
//  (b) finalize fused into gemm1 tail: block br owns queries 4br..4br+3
//      completely -> masked softmax + prior + mu/sigma computed in-block,
//      `out` written directly.  finalize kernel + ld buffer deleted.
// ---------------------------------------------------------------------------

typedef __attribute__((ext_vector_type(8))) short s16x8;
typedef __attribute__((ext_vector_type(4))) float f32x4;

static __device__ __forceinline__ unsigned short f2bf(float f) {
  unsigned u = __float_as_uint(f);
  u += 0x7fffu + ((u >> 16) & 1u);   // round-to-nearest-even
  return (unsigned short)(u >> 16);
}

static __device__ __forceinline__ void glds16(const void* g, void* l) {
  __builtin_amdgcn_global_load_lds(
      (const __attribute__((address_space(1))) void*)g,
      (__attribute__((address_space(3))) void*)l, 16, 0, 0);
}

// ---------------------------------------------------------------------------
// Merged prep kernel (unchanged from r10).
// ---------------------------------------------------------------------------
__global__ void prep_k(const float* __restrict__ qp, const float* __restrict__ qd,
                       unsigned short* __restrict__ Aq, float* __restrict__ qn,
                       const float* __restrict__ w1, const float* __restrict__ d1,
                       const float* __restrict__ be1, const float* __restrict__ w2,
                       const float* __restrict__ d2,
                       unsigned short* __restrict__ Bt1,
                       unsigned short* __restrict__ Btq,
                       unsigned short* __restrict__ Bt2c) {
  const int t = threadIdx.x;
  if (blockIdx.x < 1024) {
    const int n = blockIdx.x;
    const float4* qp4 = (const float4*)(qp + (size_t)n * 1024);
    float4 v = qp4[t];
    ushort4 o4;
    o4.x = f2bf(v.x); o4.y = f2bf(v.y); o4.z = f2bf(v.z); o4.w = f2bf(v.w);
    *(ushort4*)(Aq + (size_t)n * 1536 + t * 4) = o4;
    const float2* qd2 = (const float2*)(qd + (size_t)n * 512);
    float2 w = qd2[t];
    ushort2 o2; o2.x = f2bf(w.x); o2.y = f2bf(w.y);
    *(ushort2*)(Aq + (size_t)n * 1536 + 1024 + t * 2) = o2;
    float ss = w.x * w.x + w.y * w.y;
    #pragma unroll
    for (int m = 32; m >= 1; m >>= 1) ss += __shfl_xor(ss, m);
    __shared__ float sr[4];
    if ((t & 63) == 0) sr[t >> 6] = ss;
    __syncthreads();
    if (t == 0) qn[n] = sqrtf(sr[0] + sr[1] + sr[2] + sr[3]);
    return;
  }
  const int NB1 = 512 * 1536, NBQ = 768 * 1536, NB2 = 256 * 256;
  const int nb = gridDim.x - 1024;
  for (int idx = (blockIdx.x - 1024) * 256 + t; idx < NB1 + NBQ + NB2;
       idx += nb * 256) {
    if (idx < NB1) {
      int c = idx / 1536, j = idx - c * 1536;
      const float* W = (c < 256) ? w1 : d1;
      int cc = c & 255;
      float v;
      if (j < 1024) v = W[(1024 + j) * 256 + cc] - W[(2048 + j) * 256 + cc];
      else { int jd = j - 1024; v = W[(3584 + jd) * 256 + cc] - W[(4096 + jd) * 256 + cc]; }
      Bt1[idx] = f2bf(v);
    } else if (idx < NB1 + NBQ) {
      int i2 = idx - NB1;
      int c = i2 / 1536, j = i2 - c * 1536;
      float v;
      if (c < 512) {
        const float* W = (c < 256) ? w1 : d1;
        int cc = c & 255;
        if (j < 1024) v = W[j * 256 + cc] + W[(2048 + j) * 256 + cc];
        else { int jd = j - 1024; v = W[(3072 + jd) * 256 + cc] + W[(4096 + jd) * 256 + cc]; }
      } else {
        v = be1[j * 256 + (c - 512)];
      }
      Btq[i2] = f2bf(v);
    } else {
      int i2 = idx - NB1 - NBQ;
      int o = i2 >> 8, j = i2 & 255;
      float v = (o < 128) ? w2[j * 128 + o] : d2[j * 128 + (o - 128)];
      Bt2c[i2] = f2bf(v);
    }
  }
}

// ---------------------------------------------------------------------------
// GEMM-0: query GEMM, re-tiled 64x64, grid (16,12) = 192 blocks.
// 256 thr / 4 waves; wave w owns rows w*16..w*16+15 of the 64-row tile.
// Both operands bf16 -> glds16 staging, single-buffer 16 KB LDS.
// ---------------------------------------------------------------------------
__global__ __launch_bounds__(256) void gemm0_k(
    const unsigned short* __restrict__ abf, const unsigned short* __restrict__ Bt,
    const float* __restrict__ wb1, const float* __restrict__ db1,
    const float* __restrict__ beb1, float* __restrict__ uq_out) {
  __shared__ short As[64 * 64];   // 8 KB
  __shared__ short Bs[64 * 64];   // 8 KB
  const int tid = threadIdx.x;
  const int l = tid & 63, w = tid >> 6;
  const int br = blockIdx.x, bc = blockIdx.y;
  const int c0 = bc * 64;
  const int lc = l & 15, lk = l >> 4;
  f32x4 acc[4] = {};

  for (int kt = 0; kt < 24; ++kt) {
    const int k0 = kt * 64;
    __syncthreads();
    #pragma unroll
    for (int i = 0; i < 2; ++i) {
      int q = i * 256 + tid;               // [0,512) 16B chunks
      int row = q >> 3, slot = q & 7;
      int sw = (slot ^ (row & 7)) * 8;
      glds16(abf + (size_t)(br * 64 + row) * 1536 + k0 + sw, &As[q * 8]);
      glds16(Bt + (size_t)(c0 + row) * 1536 + k0 + sw, &Bs[q * 8]);
    }
    __syncthreads();
    #pragma unroll
    for (int kh = 0; kh < 2; ++kh) {
      int ra = w * 16 + lc;
      int sla = (kh * 4 + lk) ^ (ra & 7);
      s16x8 af = *(const s16x8*)(&As[ra * 64 + sla * 8]);
      #pragma unroll
      for (int ni = 0; ni < 4; ++ni) {
        int rb = ni * 16 + lc;
        int slb = (kh * 4 + lk) ^ (rb & 7);
        s16x8 bf = *(const s16x8*)(&Bs[rb * 64 + slb * 8]);
        acc[ni] = __builtin_amdgcn_mfma_f32_16x16x32_bf16(af, bf, acc[ni], 0, 0, 0);
      }
    }
  }
  #pragma unroll
  for (int ni = 0; ni < 4; ++ni)
    #pragma unroll
    for (int r = 0; r < 4; ++r) {
      int rowl = w * 16 + lk * 4 + r;
      int gcol = c0 + ni * 16 + lc;
      long grow = (long)br * 64 + rowl;
      float b = (gcol < 256) ? wb1[gcol]
               : (gcol < 512) ? db1[gcol - 256] : beb1[gcol - 512];
      uq_out[grow * 768 + gcol] = acc[ni][r] + b;
    }
}

// ---------------------------------------------------------------------------
// GEMM-1 (fully fused): neighbor GEMM + layer-2 + layer-3 + softmax/finalize.
// K-loop + layer-2 tail = round-10 verbatim.  New final tail: block br owns
// queries 4br..4br+3 -> masked softmax + prior + mu/sigma written to out.
// ---------------------------------------------------------------------------
__global__ __launch_bounds__(512, 2) void gemm1_k(
    const float* __restrict__ Anp, const float* __restrict__ And,
    const unsigned short* __restrict__ Bt,
    const float* __restrict__ uq, const float* __restrict__ aff,
    const float* __restrict__ ppr, const float* __restrict__ trs,
    const float* __restrict__ qd, const float* __restrict__ qn,
    const float* __restrict__ w1, const float* __restrict__ d1,
    const unsigned short* __restrict__ Bt2c,
    const float* __restrict__ wb2, const float* __restrict__ db2,
    const float* __restrict__ w3, const float* __restrict__ wb3,
    const float* __restrict__ d3, const float* __restrict__ db3,
    const int* __restrict__ msk, const float* __restrict__ be2,
    const float* __restrict__ beb2, const float* __restrict__ lsg,
    float* __restrict__ out) {
  __shared__ short As[2][128 * 64];   // 16 KB x2
  __shared__ short Bs[2][512 * 64];   // 64 KB x2  -> exactly 160 KiB
  const int tid = threadIdx.x;
  const int l = tid & 63, w = tid >> 6;
  const int wr = w >> 2, wc = w & 3;
  const long br = blockIdx.x;
  const int arow = tid >> 2, aseg = tid & 3;
  const long agrow = br * 128 + arow;
  const long an = agrow >> 5;
  const int brow = tid >> 3, bslot = tid & 7;
  const int lc = l & 15, lk = l >> 4;

  f32x4 acc[4][8] = {};
  float areg[16], qreg[16];
  float dotp = 0.f, nsp = 0.f;

  auto stageBhalf = [&](int buf, int kt, int h) {
    const int k0 = kt * 64;
    #pragma unroll
    for (int i = 0; i < 4; ++i) {
      int idx = h * 4 + i;
      int row = idx * 64 + brow;
      const unsigned short* src =
          Bt + (size_t)row * 1536 + k0 + ((bslot ^ (row & 7)) * 8);
      glds16(src, &Bs[buf][(idx * 512 + tid) * 8]);
    }
  };
  auto loadA = [&](int kt) {
    const int k0 = kt * 64 + aseg * 16;
    const float* src = (k0 < 1024) ? (Anp + agrow * 1024 + k0)
                                   : (And + agrow * 512 + (k0 - 1024));
    #pragma unroll
    for (int i = 0; i < 4; ++i) {
      float4 v = ((const float4*)src)[i];
      areg[i * 4 + 0] = v.x; areg[i * 4 + 1] = v.y;
      areg[i * 4 + 2] = v.z; areg[i * 4 + 3] = v.w;
    }
    if (kt >= 16) {                      // nd region: qd for fused cosine-sim
      const float* qs = qd + an * 512 + (k0 - 1024);
      #pragma unroll
      for (int i = 0; i < 4; ++i) {
        float4 v = ((const float4*)qs)[i];
        qreg[i * 4 + 0] = v.x; qreg[i * 4 + 1] = v.y;
        qreg[i * 4 + 2] = v.z; qreg[i * 4 + 3] = v.w;
      }
    }
  };
  auto writeA = [&](int buf, int kt) {
    if (kt >= 16) {
      #pragma unroll
      for (int j = 0; j < 16; ++j) {
        dotp += areg[j] * qreg[j];
        nsp  += areg[j] * areg[j];
      }
    }
    #pragma unroll
    for (int j = 0; j < 2; ++j) {
      int slot = (aseg * 2 + j) ^ (arow & 7);
      s16x8 pk;
      #pragma unroll
      for (int e = 0; e < 8; ++e) pk[e] = (short)f2bf(areg[j * 8 + e]);
      *(s16x8*)(&As[buf][arow * 64 + slot * 8]) = pk;
    }
  };

  auto rdA = [&](int cur, int kh, s16x8* af) {
    #pragma unroll
    for (int mi = 0; mi < 4; ++mi) {
      int ra = wr * 64 + mi * 16 + lc;
      int sl = (kh * 4 + lk) ^ (ra & 7);
      af[mi] = *(const s16x8*)(&As[cur][ra * 64 + sl * 8]);
    }
  };
  auto rdB = [&](int cur, int kh, int nh, s16x8* bfr) {
    #pragma unroll
    for (int ni = 0; ni < 4; ++ni) {
      int rb = wc * 128 + (nh * 4 + ni) * 16 + lc;
      int sl = (kh * 4 + lk) ^ (rb & 7);
      bfr[ni] = *(const s16x8*)(&Bs[cur][rb * 64 + sl * 8]);
    }
  };

  // ---- prologue: stage buffer 0 fully, full drain ----
  loadA(0);
  stageBhalf(0, 0, 0); stageBhalf(0, 0, 1);
  writeA(0, 0);
  __syncthreads();

  for (int kt = 0; kt < 24; ++kt) {
    const int cur = kt & 1, nxt = cur ^ 1;
    if (kt < 23) {
      loadA(kt + 1);
      asm volatile("s_waitcnt vmcnt(4)" ::: "memory");
    } else {
      asm volatile("s_waitcnt vmcnt(0)" ::: "memory");
    }
    asm volatile("s_waitcnt lgkmcnt(0)" ::: "memory");
    __builtin_amdgcn_s_barrier();
    __builtin_amdgcn_sched_barrier(0);

    s16x8 af[4], bfr[4];
    // ---- phase 0: kh=0, ni 0..3 ----
    rdA(cur, 0, af); rdB(cur, 0, 0, bfr);
    asm volatile("s_waitcnt lgkmcnt(0)" ::: "memory");
    __builtin_amdgcn_sched_barrier(0);
    __builtin_amdgcn_s_setprio(1);
    #pragma unroll
    for (int mi = 0; mi < 4; ++mi)
      #pragma unroll
      for (int ni = 0; ni < 4; ++ni)
        acc[mi][ni] = __builtin_amdgcn_mfma_f32_16x16x32_bf16(
            af[mi], bfr[ni], acc[mi][ni], 0, 0, 0);
    __builtin_amdgcn_s_setprio(0);
    // ---- phase 1: kh=0, ni 4..7 (+stage B half 0) ----
    if (kt < 23) stageBhalf(nxt, kt + 1, 0);
    rdB(cur, 0, 1, bfr);
    asm volatile("s_waitcnt lgkmcnt(0)" ::: "memory");
    __builtin_amdgcn_sched_barrier(0);
    __builtin_amdgcn_s_setprio(1);
    #pragma unroll
    for (int mi = 0; mi < 4; ++mi)
      #pragma unroll
      for (int ni = 0; ni < 4; ++ni)
        acc[mi][4 + ni] = __builtin_amdgcn_mfma_f32_16x16x32_bf16(
            af[mi], bfr[ni], acc[mi][4 + ni], 0, 0, 0);
    __builtin_amdgcn_s_setprio(0);
    // ---- phase 2: kh=1, ni 0..3 (+stage B half 1) ----
    if (kt < 23) stageBhalf(nxt, kt + 1, 1);
    rdA(cur, 1, af); rdB(cur, 1, 0, bfr);
    asm volatile("s_waitcnt lgkmcnt(0)" ::: "memory");
    __builtin_amdgcn_sched_barrier(0);
    __builtin_amdgcn_s_setprio(1);
    #pragma unroll
    for (int mi = 0; mi < 4; ++mi)
      #pragma unroll
      for (int ni = 0; ni < 4; ++ni)
        acc[mi][ni] = __builtin_amdgcn_mfma_f32_16x16x32_bf16(
            af[mi], bfr[ni], acc[mi][ni], 0, 0, 0);
    __builtin_amdgcn_s_setprio(0);
    // ---- phase 3: kh=1, ni 4..7 (+writeA) ----
    if (kt < 23) writeA(nxt, kt + 1);
    rdB(cur, 1, 1, bfr);
    asm volatile("s_waitcnt lgkmcnt(0)" ::: "memory");
    __builtin_amdgcn_sched_barrier(0);
    __builtin_amdgcn_s_setprio(1);
    #pragma unroll
    for (int mi = 0; mi < 4; ++mi)
      #pragma unroll
      for (int ni = 0; ni < 4; ++ni)
        acc[mi][4 + ni] = __builtin_amdgcn_mfma_f32_16x16x32_bf16(
            af[mi], bfr[ni], acc[mi][4 + ni], 0, 0, 0);
    __builtin_amdgcn_s_setprio(0);
  }

  // ---- cosine-sim reduce; simLds aliases As[0] ----
  float* simLds = (float*)&As[0][0];
  float dv = dotp, nv = nsp;
  dv += __shfl_xor(dv, 1); dv += __shfl_xor(dv, 2);
  nv += __shfl_xor(nv, 1); nv += __shfl_xor(nv, 2);
  __syncthreads();                       // all K-loop LDS reads done
  if (aseg == 0) {
    float qv = qn[an];
    simLds[arow] = dv / (fmaxf(qv, 1e-8f) * fmaxf(sqrtf(nv), 1e-8f));
  }
  __syncthreads();

  // ---- step 1: h1 tile -> LDS (Bs region), low-3-bit chunk-XOR swizzle ----
  short* h1l = &Bs[0][0];
  #pragma unroll
  for (int mi = 0; mi < 4; ++mi) {
    #pragma unroll
    for (int r = 0; r < 4; ++r) {
      int rowl = wr * 64 + mi * 16 + lk * 4 + r;
      long grow = br * 128 + rowl;
      float sa = aff[grow], sp = ppr[grow], st = trs[grow];
      float ss = simLds[rowl];
      long n = grow >> 5;
      #pragma unroll
      for (int ni = 0; ni < 8; ++ni) {
        int gcol = wc * 128 + ni * 16 + lc;
        const float* W = (gcol < 256) ? w1 : d1;
        int cc2 = gcol & 255;
        float sv = sa * W[4608 * 256 + cc2] + sp * W[4609 * 256 + cc2]
                 + st * W[4610 * 256 + cc2] + ss * W[4611 * 256 + cc2];
        float x = acc[mi][ni][r] + uq[n * 768 + gcol] + sv;
        int chsw = (gcol >> 3) ^ (rowl & 7);
        h1l[rowl * 512 + chsw * 8 + (gcol & 7)] = (short)f2bf(fmaxf(x, 0.f));
      }
    }
  }
  __syncthreads();

  // ---- step 2: layer-2 GEMM from LDS (r10 tail) ----
  short* B2 = &As[0][0];                 // [256 out][64 kk] per chunk
  f32x4 acc2[4][4] = {};
  const int rh = w >> 2;
  const int oq = w & 3;
  const int ob = oq * 64;
  const int kbase = (oq < 2) ? 0 : 256;
  for (int cc = 0; cc < 4; ++cc) {
    #pragma unroll
    for (int i = 0; i < 4; ++i) {
      int q = i * 512 + tid;             // [0,2048) 16B chunks
      int o = q >> 3, sl = q & 7;
      const unsigned short* src =
          Bt2c + (size_t)o * 256 + cc * 64 + ((sl ^ (o & 7)) * 8);
      glds16(src, &B2[q * 8]);
    }
    __syncthreads();                     // drain glds; B2 chunk ready
    #pragma unroll
    for (int kh = 0; kh < 2; ++kh) {
      s16x8 a2[4], b2f[4];
      #pragma unroll
      for (int mi = 0; mi < 4; ++mi) {
        int row = rh * 64 + mi * 16 + lc;
        int acol = kbase + cc * 64 + kh * 32 + lk * 8;
        int chsw = (acol >> 3) ^ (row & 7);
        a2[mi] = *(const s16x8*)(&h1l[row * 512 + chsw * 8]);
      }
      #pragma unroll
      for (int ni = 0; ni < 4; ++ni) {
        int o = ob + ni * 16 + lc;
        int sl = (kh * 4 + lk) ^ (o & 7);
        b2f[ni] = *(const s16x8*)(&B2[o * 64 + sl * 8]);
      }
      #pragma unroll
      for (int mi = 0; mi < 4; ++mi)
        #pragma unroll
        for (int ni = 0; ni < 4; ++ni)
          acc2[mi][ni] = __builtin_amdgcn_mfma_f32_16x16x32_bf16(
              a2[mi], b2f[ni], acc2[mi][ni], 0, 0, 0);
    }
    __syncthreads();                     // all reads of this chunk done
  }

  // ---- step 3: bias/relu + layer-3 dot; part aliases As (B2 dead) ----
  float coef[4], bb[4];
  #pragma unroll
  for (int ni = 0; ni < 4; ++ni) {
    int o = ob + ni * 16 + lc;
    coef[ni] = (o < 128) ? w3[o] : d3[o - 128];
    bb[ni]   = (o < 128) ? wb2[o] : db2[o - 128];
  }
  float* part = (float*)&As[0][0];       // [4 oq][128 rows]
  #pragma unroll
  for (int mi = 0; mi < 4; ++mi) {
    #pragma unroll
    for (int rr = 0; rr < 4; ++rr) {
      float p = 0.f;
      #pragma unroll
      for (int ni = 0; ni < 4; ++ni)
        p += fmaxf(acc2[mi][ni][rr] + bb[ni], 0.f) * coef[ni];
      p += __shfl_xor(p, 1); p += __shfl_xor(p, 2);
      p += __shfl_xor(p, 4); p += __shfl_xor(p, 8);
      if (lc == 0)
        part[oq * 128 + rh * 64 + mi * 16 + lk * 4 + rr] = p;
    }
  }
  __syncthreads();

  // ---- step 4: fused finalize.  Waves 0,1: 2 queries/wave, 32 lanes each.
  //      q index: n = br*4 + w*2 + (l>>5); neighbor kk = l&31.
  //      All shuffles use xor<=16 (stay within the 32-lane half). ----
  if (w < 2) {
    const int half = l >> 5, kk = l & 31;
    const int rowl = (w * 2 + half) * 32 + kk;
    const long n = br * 4 + w * 2 + half;
    float lgt = part[0 * 128 + rowl] + part[1 * 128 + rowl] + wb3[0];
    float dlt = part[2 * 128 + rowl] + part[3 * 128 + rowl] + db3[0];
    // binding-encoder prior partial: 8 elems/lane over uq[n,512:768]
    float pp = 0.f;
    const float* uqr = uq + (size_t)n * 768 + 512 + kk * 8;
    #pragma unroll
    for (int j = 0; j < 8; ++j)
      pp += fmaxf(uqr[j], 0.f) * be2[kk * 8 + j];
    #pragma unroll
    for (int mm = 16; mm >= 1; mm >>= 1) pp += __shfl_xor(pp, mm);
    // masked softmax over the 32 neighbors
    int m = msk[n * 32 + kk];
    float lg = m ? lgt : -1e9f;
    float mx = lg;
    #pragma unroll
    for (int mm = 16; mm >= 1; mm >>= 1) mx = fmaxf(mx, __shfl_xor(mx, mm));
    float e = expf(lg - mx);
    float s = e;
    #pragma unroll
    for (int mm = 16; mm >= 1; mm >>= 1) s += __shfl_xor(s, mm);
    float wgt = (e / s) * (m ? 1.f : 0.f);
    float nrm = wgt;
    #pragma unroll
    for (int mm = 16; mm >= 1; mm >>= 1) nrm += __shfl_xor(nrm, mm);
    wgt = (nrm > 0.f) ? wgt / fmaxf(nrm, 1e-8f) : 0.f;
    float tr = wgt * aff[n * 32 + kk];
    float co = wgt * dlt;
    int am = m;
    #pragma unroll
    for (int mm = 16; mm >= 1; mm >>= 1) {
      tr += __shfl_xor(tr, mm);
      co += __shfl_xor(co, mm);
      am |= __shfl_xor(am, mm);
    }
    if (kk == 0) {
      float prior = pp + beb2[0] + 6.5f;
      float l0 = lsg[0];
      float sp = (l0 > 20.f) ? l0 : log1pf(expf(l0));
      out[n] = am ? (tr + co) : prior;
      out[1024 + n] = sp + (am ? 0.f : 0.15f) + 1e-4f;
    }
  }
}

// ---------------------------------------------------------------------------
extern "C" void kernel_launch(void* const* d_in, const int* in_sizes, int n_in,
                              void* d_out, int out_size, void* d_ws, size_t ws_size,
                              hipStream_t stream) {
  const float* np_ = (const float*)d_in[0];
  const float* nd_ = (const float*)d_in[1];
  const float* aff = (const float*)d_in[2];
  const float* ppr = (const float*)d_in[3];
  const float* trs = (const float*)d_in[4];
  const int*   msk = (const int*)d_in[5];
  const float* qp  = (const float*)d_in[6];
  const float* qd  = (const float*)d_in[7];
  const float* w1  = (const float*)d_in[8];
  const float* wb1 = (const float*)d_in[9];
  const float* w2  = (const float*)d_in[10];
  const float* wb2 = (const float*)d_in[11];
  const float* w3  = (const float*)d_in[12];
  const float* wb3 = (const float*)d_in[13];
  const float* d1  = (const float*)d_in[14];
  const float* db1 = (const float*)d_in[15];
  const float* d2  = (const float*)d_in[16];
  const float* db2 = (const float*)d_in[17];
  const float* d3  = (const float*)d_in[18];
  const float* db3 = (const float*)d_in[19];
  const float* be1 = (const float*)d_in[20];
  const float* beb1 = (const float*)d_in[21];
  const float* be2 = (const float*)d_in[22];
  const float* beb2 = (const float*)d_in[23];
  const float* lsg = (const float*)d_in[24];
  float* out = (float*)d_out;

  char* ws = (char*)d_ws;
  size_t off = 0;
  auto carve = [&](size_t bytes) -> void* {
    void* p = ws + off;
    off += (bytes + 511) & ~(size_t)511;
    return p;
  };
  float*          uq   = (float*)carve(1024ull * 768 * 4);
  unsigned short* Bt1  = (unsigned short*)carve(512ull * 1536 * 2);
  unsigned short* Btq  = (unsigned short*)carve(768ull * 1536 * 2);
  unsigned short* Bt2c = (unsigned short*)carve(256ull * 256 * 2);
  unsigned short* Aq   = (unsigned short*)carve(1024ull * 1536 * 2);
  float*          qn   = (float*)carve(1024ull * 4);
  (void)ws_size; (void)in_sizes; (void)n_in; (void)out_size;

  prep_k<<<3072, 256, 0, stream>>>(qp, qd, Aq, qn,
                                   w1, d1, be1, w2, d2, Bt1, Btq, Bt2c);

  gemm0_k<<<dim3(16, 12), 256, 0, stream>>>(Aq, Btq, wb1, db1, beb1, uq);

  gemm1_k<<<256, 512, 0, stream>>>(np_, nd_, Bt1, uq, aff, ppr, trs,
                                   qd, qn, w1, d1,
                                   Bt2c, wb2, db2, w3, wb3, d3, db3,
                                   msk, be2, beb2, lsg, out);
}